// Round 11
// baseline (337.697 us; speedup 1.0000x reference)
//
#include <hip/hip_runtime.h>
#include <stdint.h>

typedef __attribute__((ext_vector_type(4))) float f32x4;
typedef __attribute__((ext_vector_type(8))) short s16x8;
typedef unsigned short us;

static __device__ __forceinline__ us f2bf(float f) {
  union { float f; uint32_t u; } v; v.f = f;
  uint32_t u = v.u;
  u += 0x7fffu + ((u >> 16) & 1u);   // round-to-nearest-even bf16
  return (us)(u >> 16);
}

// mode: 0 none, 1 multiply, 2 multiply-by-safe-reciprocal
static __device__ __forceinline__ float dval(const float* dv, long r, long dstr, int mode) {
  if (!dv || mode == 0) return 1.f;
  float d = dv[r * dstr];
  if (mode == 2) return (d != 0.f) ? 1.f / d : 0.f;
  return d;
}

// ============ FRAGMENT-DUMP LAYOUTS ============
// X-panel dump (32 cols): element (c, k) at us-offset
//   (k>>6)*2048 + (((k>>5)&1)*2 + (c>>4))*512 + ((c&15) | (((k>>3)&3)<<4))*8 + (k&7)
// A dump (row-major source): element (row, k) at us-offset
//   ((row>>4)*nkstep + (k>>6))*1024 + ((k>>5)&1)*512 + ((row&15) | (((k>>3)&3)<<4))*8 + (k&7)
// Both make GEMM fragment loads lane-contiguous (1KB per wave load).

// ---------------- transpose tile: src f32 [n][32] -> X-frag dump ----------------
static __device__ void tpose_tile(const float* __restrict__ src, long lds_, int n,
                                  const float* __restrict__ dv, long dstr, int mode,
                                  us* __restrict__ dst, int ldn, int tile,
                                  us (*sm)[72]) {
  const int t = threadIdx.x;
  const int r0 = tile * 64;
  {
    const int rr = t & 63;
    const int cg = t >> 6;
    const int gr = r0 + rr;
    float sc = 1.f;
    f32x4 v0 = {0.f, 0.f, 0.f, 0.f}, v1 = {0.f, 0.f, 0.f, 0.f};
    if (gr < n) {
      sc = dval(dv, gr, dstr, mode);
      const float* sp = src + (long)gr * lds_ + cg * 8;
      v0 = *(const f32x4*)sp;
      v1 = *(const f32x4*)(sp + 4);
    }
#pragma unroll
    for (int j = 0; j < 4; ++j) {
      sm[cg * 8 + j][rr] = f2bf(v0[j] * sc);
      sm[cg * 8 + 4 + j][rr] = f2bf(v1[j] * sc);
    }
  }
  __syncthreads();
  {
    const int f = t >> 3;          // col 0..31
    const int low = t & 7;         // k'-octet
    const int kk = low >> 2, q = low & 3;
    const int lane = (f & 15) | (q << 4);
    const int nt = f >> 4;
    size_t off = (size_t)tile * 2048 + (size_t)(kk * 2 + nt) * 512 + (size_t)lane * 8;
    *(s16x8*)(dst + off) = *(const s16x8*)&sm[f][low * 8];
  }
  (void)ldn;
}

// ---------------- convT tile: in f32 [nI][ldi] -> out = in^T as A-frag dump ----------------
static __device__ void convT_tile(const float* __restrict__ in, int ldi, int nI, int nC,
                                  us* __restrict__ outT, int nkstep, int bx, int by,
                                  us (*sT)[72]) {
  const int t = threadIdx.x;
  const int tc0 = bx * 64;   // in-col tile = out-row tile
  const int tr0 = by * 64;   // in-row tile = out-k tile (kstep = tr0>>6)
  const int c0 = (t & 15) * 4;
  const int r0 = (t >> 4) * 4;
  us ub[4][4];
#pragma unroll
  for (int j = 0; j < 4; ++j) {
    int gr = tr0 + r0 + j;
    f32x4 v = {0.f, 0.f, 0.f, 0.f};
    if (gr < nI) {
      const float* pI = in + (size_t)gr * ldi + tc0 + c0;
      if (tc0 + c0 + 3 < nC) {
        v = *(const f32x4*)pI;
      } else {
#pragma unroll
        for (int jj = 0; jj < 4; ++jj) if (tc0 + c0 + jj < nC) v[jj] = pI[jj];
      }
    }
#pragma unroll
    for (int jj = 0; jj < 4; ++jj) ub[j][jj] = f2bf(v[jj]);
  }
#pragma unroll
  for (int jj = 0; jj < 4; ++jj) {
    union { us u[4]; unsigned long long ll; } w;
#pragma unroll
    for (int j = 0; j < 4; ++j) w.u[j] = ub[j][jj];
    *(unsigned long long*)&sT[c0 + jj][r0] = w.ll;   // sT[out-row][out-k]
  }
  __syncthreads();
#pragma unroll
  for (int p = 0; p < 2; ++p) {
    const int orow = (t >> 3) + p * 32;   // out-row within tile
    const int low = t & 7;
    const int kk = low >> 2, q = low & 3;
    const int lane = (orow & 15) | (q << 4);
    size_t off = ((size_t)((tc0 >> 4) + (orow >> 4)) * nkstep + (tr0 >> 6)) * 1024
               + (size_t)kk * 512 + (size_t)lane * 8;
    *(s16x8*)(outT + off) = *(const s16x8*)&sT[orow][low * 8];
  }
}

// ---------------- batched small transpose (standalone) ----------------
struct TSeg { const float* src; us* dst; int lds_, n, ldn, start; };
struct TPack { TSeg t[8]; int nseg; };

__global__ __launch_bounds__(256) void tpose_batch(TPack P) {
  __shared__ us sm[32][72];
  int b = blockIdx.x;
  int si = P.nseg - 1;
  while (si > 0 && P.t[si].start > b) --si;
  const TSeg s = P.t[si];
  tpose_tile(s.src, s.lds_, s.n, nullptr, 0, 0, s.dst, s.ldn, b - s.start, sm);
}

// ---------------- prep ----------------
__global__ __launch_bounds__(256) void prep(
    const float* __restrict__ x0, const float* __restrict__ x1, const float* __restrict__ x2,
    const float* __restrict__ D1, const float* __restrict__ D3, const float* __restrict__ D5,
    const float* __restrict__ W0, const float* __restrict__ W1, const float* __restrict__ W2,
    us* x0T, us* x0dT, us* x1T, us* x1dT, us* x2T, us* x2dT,
    us* W0T, us* W1T, us* W2T,
    float* __restrict__ X0a, float* __restrict__ X1a, float* __restrict__ X2a) {
  __shared__ us sm[32][72];
  int b = blockIdx.x;
  if (b < 24)  { tpose_tile(x0, 32, 1500, nullptr, 0, 0, x0T, 1536, b, sm); return; }
  b -= 24;
  if (b < 24)  { tpose_tile(x0, 32, 1500, D1, 1501, 2, x0dT, 1536, b, sm); return; }
  b -= 24;
  if (b < 94)  { tpose_tile(x1, 32, 6000, nullptr, 0, 0, x1T, 6016, b, sm); return; }
  b -= 94;
  if (b < 94)  { tpose_tile(x1, 32, 6000, D5, 6001, 2, x1dT, 6016, b, sm); return; }
  b -= 94;
  if (b < 64)  { tpose_tile(x2, 32, 4000, nullptr, 0, 0, x2T, 4096, b, sm); return; }
  b -= 64;
  if (b < 64)  { tpose_tile(x2, 32, 4000, D3, 4001, 1, x2dT, 4096, b, sm); return; }
  b -= 64;
  if (b < 3) {
    const float* W = (b == 0) ? W0 : ((b == 1) ? W1 : W2);
    us* dst = (b == 0) ? W0T : ((b == 1) ? W1T : W2T);
    const int K = (b == 1) ? 11 : 6;
    const int C = K * 32;
    const int CP = (b == 1) ? 384 : 192;
    for (int idx = threadIdx.x; idx < 32 * CP; idx += 256) {
      int o = idx / CP, k = idx - o * CP;
      float v = 0.f;
      if (k < C) { int kw = k >> 5, i = k & 31; v = W[((long)i * 32 + o) * K + kw]; }
      size_t off = (size_t)(k >> 6) * 2048 + (size_t)(((k >> 5) & 1) * 2 + (o >> 4)) * 512
                 + (size_t)((o & 15) | (((k >> 3) & 3) << 4)) * 8 + (k & 7);
      dst[off] = f2bf(v);
    }
    return;
  }
  b -= 3;
  const long V0 = 1500L * 48, V1 = 6000L * 88, V2 = 4000L * 48;
  for (long i = (long)b * 256 + threadIdx.x; i < V0 + V1 + V2; i += 512L * 256) {
    f32x4 v = {0.f, 0.f, 0.f, 0.f};
    float* dst;
    if (i < V0) {
      long r = i / 48; int c0 = (int)(i - r * 48) * 4;
      if (c0 < 32) v = *(const f32x4*)(x0 + r * 32 + c0);
      dst = X0a + r * 192 + c0;
    } else if (i < V0 + V1) {
      long j = i - V0; long r = j / 88; int c0 = (int)(j - r * 88) * 4;
      if (c0 >= 96 && c0 < 128) v = *(const f32x4*)(x1 + r * 32 + (c0 - 96));
      dst = X1a + r * 352 + c0;
    } else {
      long j = i - V0 - V1; long r = j / 48; int c0 = (int)(j - r * 48) * 4;
      if (c0 >= 96 && c0 < 128) v = *(const f32x4*)(x2 + r * 32 + (c0 - 96));
      dst = X2a + r * 192 + c0;
    }
    *(f32x4*)dst = v;
  }
}

// ---------------- mega: fragment-direct GEMM (no LDS, no barriers) + convT/tpose segs ----------------
struct Seg {
  const void* A; us* Aout;
  const us* Bt0; const us* Bt1;
  const float* S0; const float* S1; const float* sv;
  float* C0; float* C1;
  float alpha, beta;
  int lda, ldao, ldS, sstr, ldc;     // lda: f32 row stride OR bf16-dump nkstep; ldao: Aout nkstep
  int n_rows, n_k, smode, kchunk, tiles, ky, start;
};
struct CSeg { const float* in; us* out; int ldi, nI, nC, nkstep, cx, start; };
struct Mega {
  Seg s[4]; CSeg c[2]; TSeg t[2];
  int nseg, gemm_end, nconv, conv_end, ntp;
};

template <int F, bool RELU, int AMODE>   // AMODE: 0 = f32 row-major, 1 = bf16 frag-dump
__global__ __launch_bounds__(256) void mega(Mega P) {
  __shared__ us sm[64][72];
  const int b = blockIdx.x;
  if (b >= P.gemm_end) {
    if (b < P.conv_end) {
      int lb = b - P.gemm_end;
      int si = P.nconv - 1;
      while (si > 0 && P.c[si].start > lb) --si;
      const CSeg s = P.c[si];
      int l = lb - s.start;
      convT_tile(s.in, s.ldi, s.nI, s.nC, s.out, s.nkstep, l % s.cx, l / s.cx, sm);
    } else {
      int lb = b - P.conv_end;
      int si = P.ntp - 1;
      while (si > 0 && P.t[si].start > lb) --si;
      const TSeg s = P.t[si];
      tpose_tile(s.src, s.lds_, s.n, nullptr, 0, 0, s.dst, s.ldn, lb - s.start,
                 (us(*)[72])sm);
    }
    return;
  }

  constexpr int NT = F / 16;
  int si = P.nseg - 1;
  while (si > 0 && P.s[si].start > b) --si;
  const Seg sg = P.s[si];
  const int local = b - sg.start;
  const int bx = local % sg.tiles;
  const int kidx = local / sg.tiles;

  const int tid = threadIdx.x;
  const int w = tid >> 6;
  const int lane = tid & 63;
  const int r = lane & 15;
  const int g = lane >> 4;

  const int n_rows = sg.n_rows, n_k = sg.n_k;
  const long arow = (long)bx * 64 + w * 16 + r;
  const bool arow_ok = arow < n_rows;
  const int rowblk = bx * 4 + w;

  const int k_begin = kidx * sg.kchunk;
  const int k_end = min(n_k, k_begin + sg.kchunk);
  const int nsteps = (k_end - k_begin + 63) >> 6;

  const float* Af = nullptr;
  const us* Ad = nullptr;
  if (AMODE == 0) Af = (const float*)sg.A + (size_t)(arow_ok ? arow : 0) * sg.lda;
  else Ad = (const us*)sg.A + ((size_t)rowblk * sg.lda) * 1024 + lane * 8;

  f32x4 aA[4], aB[4];
  s16x8 abA[2], abB[2];
  s16x8 xA[2 * NT], xB[2 * NT];

  auto LD = [&](int s, f32x4* av, s16x8* abv, s16x8* xv) {
    const int k0 = k_begin + s * 64;
    const int kstep = k0 >> 6;
    if constexpr (AMODE == 0) {
#pragma unroll
      for (int kk = 0; kk < 2; ++kk) {
        const int kc = k0 + kk * 32 + g * 8;
        f32x4 u0 = {0.f, 0.f, 0.f, 0.f}, u1 = {0.f, 0.f, 0.f, 0.f};
        if (arow_ok) {
          const float* ap = Af + kc;
          if (kc + 8 <= n_k) {
            u0 = *(const f32x4*)ap; u1 = *(const f32x4*)(ap + 4);
          } else {
#pragma unroll
            for (int j = 0; j < 4; ++j) {
              if (kc + j < n_k) u0[j] = ap[j];
              if (kc + 4 + j < n_k) u1[j] = ap[4 + j];
            }
          }
        }
        av[kk * 2] = u0; av[kk * 2 + 1] = u1;
      }
    } else {
      const us* ap = Ad + (size_t)kstep * 1024;
      abv[0] = *(const s16x8*)ap;
      abv[1] = *(const s16x8*)(ap + 512);
    }
#pragma unroll
    for (int kk = 0; kk < 2; ++kk)
#pragma unroll
      for (int nt = 0; nt < NT; ++nt) {
        const us* xp = (NT == 4 && nt >= 2) ? sg.Bt1 : sg.Bt0;
        xv[kk * NT + nt] = *(const s16x8*)(xp + ((size_t)kstep * 4 + kk * 2 + (nt & 1)) * 512
                                           + lane * 8);
      }
  };

  f32x4 acc[NT];
#pragma unroll
  for (int i = 0; i < NT; ++i) acc[i] = f32x4{0.f, 0.f, 0.f, 0.f};

  auto CMP = [&](int s, f32x4* av, s16x8* abv, s16x8* xv) {
    s16x8 pa0, pa1;
    if constexpr (AMODE == 0) {
#pragma unroll
      for (int j = 0; j < 4; ++j) {
        pa0[j] = (short)f2bf(av[0][j]); pa0[4 + j] = (short)f2bf(av[1][j]);
        pa1[j] = (short)f2bf(av[2][j]); pa1[4 + j] = (short)f2bf(av[3][j]);
      }
      if (sg.Aout && arow_ok) {
        const int kstep = (k_begin + s * 64) >> 6;
        us* q = sg.Aout + ((size_t)rowblk * sg.ldao + kstep) * 1024 + lane * 8;
        *(s16x8*)q = pa0;
        *(s16x8*)(q + 512) = pa1;
      }
    } else { pa0 = abv[0]; pa1 = abv[1]; (void)s; }
#pragma unroll
    for (int nt = 0; nt < NT; ++nt)
      acc[nt] = __builtin_amdgcn_mfma_f32_16x16x32_bf16(pa0, xv[nt], acc[nt], 0, 0, 0);
#pragma unroll
    for (int nt = 0; nt < NT; ++nt)
      acc[nt] = __builtin_amdgcn_mfma_f32_16x16x32_bf16(pa1, xv[NT + nt], acc[nt], 0, 0, 0);
  };

  if (nsteps > 0) LD(0, aA, abA, xA);
  int s = 0;
  for (; s + 1 < nsteps; s += 2) {
    LD(s + 1, aB, abB, xB);
    CMP(s, aA, abA, xA);
    if (s + 2 < nsteps) LD(s + 2, aA, abA, xA);
    CMP(s + 1, aB, abB, xB);
  }
  if (s < nsteps) CMP(s, aA, abA, xA);

  float svv[4];
#pragma unroll
  for (int j = 0; j < 4; ++j) {
    long row = (long)bx * 64 + w * 16 + g * 4 + j;
    svv[j] = (row < n_rows) ? dval(sg.sv, row, sg.sstr, sg.smode) : 0.f;
  }
#pragma unroll
  for (int nt = 0; nt < NT; ++nt) {
    float* C = (F == 64 && nt >= 2) ? sg.C1 : sg.C0;
    const float* S = (F == 64 && nt >= 2) ? sg.S1 : sg.S0;
    int col = ((F == 64) ? (nt & 1) : nt) * 16 + r;
#pragma unroll
    for (int j = 0; j < 4; ++j) {
      long row = (long)bx * 64 + w * 16 + g * 4 + j;
      if (row < n_rows) {
        float v = sg.alpha * acc[nt][j] * svv[j];
        if (S && (sg.ky == 1 || kidx == 0)) v += sg.beta * S[row * (size_t)sg.ldS + col];
        if (sg.ky > 1) {
          atomicAdd(&C[row * (size_t)sg.ldc + col], v);
        } else {
          if (RELU) v = fmaxf(v, 0.0f);
          C[row * (size_t)sg.ldc + col] = v;
        }
      }
    }
  }
}

// ---------------- fallback helpers ----------------
__global__ void colcopy(float* __restrict__ dst, const float* __restrict__ src, int n,
                        const float* __restrict__ dv, long dstr, int mode) {
  int idx = blockIdx.x * 256 + threadIdx.x;
  if (idx >= n * 32) return;
  dst[idx] = src[idx] * dval(dv, idx >> 5, dstr, mode);
}
__global__ void scale_ld(float* __restrict__ dst, long ld, int n,
                         const float* __restrict__ dv, long dstr, int mode) {
  int idx = blockIdx.x * 256 + threadIdx.x;
  if (idx >= n * 32) return;
  dst[(size_t)(idx >> 5) * ld + (idx & 31)] *= dval(dv, idx >> 5, dstr, mode);
}
__global__ __launch_bounds__(256) void mm_at(
    const float* __restrict__ A, int lda, int m,
    const float* __restrict__ X,
    float* __restrict__ C, int ldc, int n, int kchunk) {
  const int fg = threadIdx.x & 3;
  const int cg = threadIdx.x >> 2;
  const int c = blockIdx.x * 256 + cg * 4;
  const int k0 = blockIdx.y * kchunk;
  const int k1 = min(m, k0 + kchunk);
  const int f = fg * 8;
  float acc[4][8];
#pragma unroll
  for (int a = 0; a < 4; ++a)
#pragma unroll
    for (int bb = 0; bb < 8; ++bb) acc[a][bb] = 0.f;
  for (int k = k0; k < k1; ++k) {
    const float* Ar = A + (size_t)k * lda + c;
    f32x4 a;
    if (c + 3 < n) a = *(const f32x4*)Ar;
    else {
      a = f32x4{0.f, 0.f, 0.f, 0.f};
#pragma unroll
      for (int j = 0; j < 4; ++j) if (c + j < n) a[j] = Ar[j];
    }
    f32x4 xa = *(const f32x4*)(X + (size_t)k * 32 + f);
    f32x4 xb = *(const f32x4*)(X + (size_t)k * 32 + f + 4);
#pragma unroll
    for (int cc = 0; cc < 4; ++cc)
#pragma unroll
      for (int jj = 0; jj < 4; ++jj) {
        acc[cc][jj] += a[cc] * xa[jj];
        acc[cc][4 + jj] += a[cc] * xb[jj];
      }
  }
  if (c >= n) return;
#pragma unroll
  for (int cc = 0; cc < 4; ++cc) {
    if (c + cc >= n) break;
#pragma unroll
    for (int jj = 0; jj < 8; ++jj)
      atomicAdd(&C[(size_t)(c + cc) * ldc + f + jj], acc[cc][jj]);
  }
}

// ---------------- host ----------------

extern "C" void kernel_launch(void* const* d_in, const int* in_sizes, int n_in,
                              void* d_out, int out_size, void* d_ws, size_t ws_size,
                              hipStream_t stream) {
  (void)in_sizes; (void)n_in; (void)out_size;
  const float* x0  = (const float*)d_in[0];
  const float* x1  = (const float*)d_in[1];
  const float* x2  = (const float*)d_in[2];
  const float* B1  = (const float*)d_in[3];
  const float* B2  = (const float*)d_in[4];
  const float* L0  = (const float*)d_in[5];
  const float* L1l = (const float*)d_in[6];
  const float* L1u = (const float*)d_in[7];
  const float* L2  = (const float*)d_in[8];
  const float* D1  = (const float*)d_in[9];
  const float* D2  = (const float*)d_in[10];
  const float* D3  = (const float*)d_in[11];
  const float* D5  = (const float*)d_in[12];
  const float* W0  = (const float*)d_in[13];
  const float* W1  = (const float*)d_in[14];
  const float* W2  = (const float*)d_in[15];
  float* out = (float*)d_out;

  char* p = (char*)d_ws;
  auto alloc = [&](size_t bsz) { char* r = p; p += (bsz + 255) & ~(size_t)255; return r; };

  // X-panel frag dumps: (ld/64) * 4096 B
  us* x0T   = (us*)alloc((size_t)24 * 4096);
  us* x0dT  = (us*)alloc((size_t)24 * 4096);
  us* x1T   = (us*)alloc((size_t)94 * 4096);
  us* x1dT  = (us*)alloc((size_t)94 * 4096);
  us* x2T   = (us*)alloc((size_t)64 * 4096);
  us* x2dT  = (us*)alloc((size_t)64 * 4096);
  us* x0pT  = (us*)alloc((size_t)24 * 4096);
  us* x1nT  = (us*)alloc((size_t)94 * 4096);
  us* x1pT  = (us*)alloc((size_t)94 * 4096);
  us* x2nT  = (us*)alloc((size_t)64 * 4096);
  us* T1a0T = (us*)alloc((size_t)24 * 4096);
  us* T1b0T = (us*)alloc((size_t)24 * 4096);
  us* T1laT = (us*)alloc((size_t)94 * 4096);
  us* T1lbT = (us*)alloc((size_t)94 * 4096);
  us* T1uaT = (us*)alloc((size_t)94 * 4096);
  us* T1ubT = (us*)alloc((size_t)94 * 4096);
  us* T1a2T = (us*)alloc((size_t)64 * 4096);
  us* T1b2T = (us*)alloc((size_t)64 * 4096);
  us* W0T   = (us*)alloc((size_t)3 * 4096);
  us* W1T   = (us*)alloc((size_t)6 * 4096);
  us* W2T   = (us*)alloc((size_t)3 * 4096);

  float* X0a = (float*)alloc((size_t)1500 * 192 * 4);
  float* X1a = (float*)alloc((size_t)6000 * 352 * 4);
  float* X2a = (float*)alloc((size_t)4000 * 192 * 4);

  float* z0  = (float*)alloc((size_t)1500 * 32 * 4);
  float* sx1 = (float*)alloc((size_t)6000 * 32 * 4);

  // A-frag dumps: rowblk16 * nkstep * 2048 B
  const size_t szB1t = (size_t)376 * 24 * 2048;
  const size_t szB2t = (size_t)252 * 94 * 2048;
  const size_t szL0  = (size_t)96 * 24 * 2048;
  const size_t szL1  = (size_t)376 * 94 * 2048;
  const size_t szL2  = (size_t)252 * 64 * 2048;

  size_t used = (size_t)(p - (char*)d_ws);
  const size_t needB  = szB1t + szB2t + 1024;
  const size_t needL1 = 2 * szL1 + 1024;
  const size_t needL02 = szL0 + szL2 + 1024;
  bool haveB = used + needB <= ws_size;
  int tier = 0;
  if (haveB) {
    if (used + needB + needL1 + needL02 <= ws_size) tier = 2;
    else if (used + needB + needL1 <= ws_size) tier = 1;
  }
  us *B1t = nullptr, *B2t = nullptr;
  us *L0bf = nullptr, *L1lbf = nullptr, *L1ubf = nullptr, *L2bf = nullptr;
  if (haveB) { B1t = (us*)alloc(szB1t); B2t = (us*)alloc(szB2t); }
  if (tier >= 1) { L1lbf = (us*)alloc(szL1); L1ubf = (us*)alloc(szL1); }
  if (tier >= 2) { L0bf = (us*)alloc(szL0); L2bf = (us*)alloc(szL2); }

  auto nb = [](long t) { return (unsigned)((t + 255) / 256); };
  auto seg = [](const void* A, us* Aout, int lda, int ldao, int n_rows, int n_k,
                const us* Bt0, const us* Bt1,
                float alpha, const float* S0, const float* S1, int ldS, float beta,
                const float* sv, int sstr, int smode,
                float* C0, float* C1, int ldc,
                int kchunk, int tiles, int ky, int start) {
    Seg s;
    s.A = A; s.Aout = Aout; s.Bt0 = Bt0; s.Bt1 = Bt1; s.S0 = S0; s.S1 = S1; s.sv = sv;
    s.C0 = C0; s.C1 = C1; s.alpha = alpha; s.beta = beta;
    s.lda = lda; s.ldao = ldao; s.ldS = ldS; s.sstr = sstr; s.ldc = ldc;
    s.n_rows = n_rows; s.n_k = n_k; s.smode = smode;
    s.kchunk = kchunk; s.tiles = tiles; s.ky = ky; s.start = start;
    return s;
  };

  // 1. prep
  prep<<<879, 256, 0, stream>>>(x0, x1, x2, D1, D3, D5, W0, W1, W2,
                                x0T, x0dT, x1T, x1dT, x2T, x2dT, W0T, W1T, W2T,
                                X0a, X1a, X2a);

  // M1: B-GEMMs (x0p, x1p) + convT(B1->B1t, B2->B2t)
  {
    Mega P{};
    P.nseg = 2;
    P.s[0] = seg(B1, nullptr, 6000, 0, 1500, 6000, x1T, x1T,
                 1.f, nullptr, nullptr, 0, 0.f, D1, 1501, 2,
                 X0a + 3 * 32, nullptr, 192, 768, 24, 8, 0);               // 192
    P.s[1] = seg(B2, nullptr, 4000, 0, 6000, 4000, x2dT, x2dT,
                 1.f, nullptr, nullptr, 0, 0.f, nullptr, 0, 0,
                 X1a + 8 * 32, nullptr, 352, 512, 94, 8, 192);             // 752
    P.gemm_end = 944;
    if (haveB) {
      P.nconv = 2;
      P.c[0] = CSeg{B1, B1t, 6000, 1500, 6000, 24, 94, 0};
      P.c[1] = CSeg{B2, B2t, 4000, 6000, 4000, 94, 63, 2256};
      P.conv_end = 944 + 2256 + 5922;
    } else {
      P.nconv = 0; P.conv_end = 944;
    }
    P.ntp = 0;
    mega<32, false, 0><<<P.conv_end, 256, 0, stream>>>(P);
  }

  // M2: Bt-GEMMs (x1n, x2n) + tpose(x0p, x1p)
  if (haveB) {
    Mega P{};
    P.nseg = 2;
    P.s[0] = seg(B1t, nullptr, 24, 0, 6000, 1536, x0dT, x0dT,
                 1.f, nullptr, nullptr, 0, 0.f, D2, 6001, 1,
                 X1a + 0 * 32, nullptr, 352, 384, 94, 4, 0);               // 376
    P.s[1] = seg(B2t, nullptr, 94, 0, 4000, 6016, x1dT, x1dT,
                 1.f, nullptr, nullptr, 0, 0.f, nullptr, 0, 0,
                 X2a + 0 * 32, nullptr, 192, 768, 63, 8, 376);             // 504
    P.gemm_end = 880;
    P.nconv = 0; P.conv_end = 880;
    P.ntp = 2;
    P.t[0] = TSeg{X0a + 3 * 32, x0pT, 192, 1500, 1536, 0};
    P.t[1] = TSeg{X1a + 8 * 32, x1pT, 352, 6000, 6016, 24};
    mega<32, false, 1><<<998, 256, 0, stream>>>(P);
  } else {
    colcopy<<<nb(1500L * 32), 256, 0, stream>>>(z0, x0, 1500, D1, 1501, 2);
    mm_at<<<dim3(24, 24), 256, 0, stream>>>(B1, 6000, 1500, z0, X1a + 0 * 32, 352, 6000, 63);
    scale_ld<<<nb(6000L * 32), 256, 0, stream>>>(X1a + 0 * 32, 352, 6000, D2, 6001, 1);
    colcopy<<<nb(6000L * 32), 256, 0, stream>>>(sx1, x1, 6000, D5, 6001, 2);
    mm_at<<<dim3(16, 32), 256, 0, stream>>>(B2, 4000, 6000, sx1, X2a + 0 * 32, 192, 4000, 188);
    TPack T{};
    T.nseg = 2;
    T.t[0] = TSeg{X0a + 3 * 32, x0pT, 192, 1500, 1536, 0};
    T.t[1] = TSeg{X1a + 8 * 32, x1pT, 352, 6000, 6016, 24};
    tpose_batch<<<118, 256, 0, stream>>>(T);
  }

  // M3: tpose x1n, x2n
  {
    TPack T{};
    T.nseg = 2;
    T.t[0] = TSeg{X1a + 0 * 32, x1nT, 352, 6000, 6016, 0};
    T.t[1] = TSeg{X2a + 0 * 32, x2nT, 192, 4000, 4096, 94};
    tpose_batch<<<158, 256, 0, stream>>>(T);
  }

  // M4: cheb pass 1 (T1 = L @ [a|b]) + bf16-L frag-dump side product
  {
    Mega P{};
    P.nseg = 4;
    P.s[0] = seg(L0, L0bf, 1500, 24, 1500, 1500, x0T, x0pT,
                 1.f, nullptr, nullptr, 0, 0.f, nullptr, 0, 0,
                 X0a + 1 * 32, X0a + 4 * 32, 192, 384, 24, 4, 0);          // 96
    P.s[1] = seg(L1l, L1lbf, 6000, 94, 6000, 6000, x1nT, x1T,
                 1.f, nullptr, nullptr, 0, 0.f, nullptr, 0, 0,
                 X1a + 1 * 32, X1a + 4 * 32, 352, 768, 94, 8, 96);         // 752
    P.s[2] = seg(L1u, L1ubf, 6000, 94, 6000, 6000, x1T, x1pT,
                 1.f, nullptr, nullptr, 0, 0.f, nullptr, 0, 0,
                 X1a + 6 * 32, X1a + 9 * 32, 352, 768, 94, 8, 848);        // 752
    P.s[3] = seg(L2, L2bf, 4000, 64, 4000, 4000, x2nT, x2T,
                 1.f, nullptr, nullptr, 0, 0.f, nullptr, 0, 0,
                 X2a + 1 * 32, X2a + 4 * 32, 192, 512, 63, 8, 1600);       // 504
    P.gemm_end = 2104; P.nconv = 0; P.conv_end = 2104; P.ntp = 0;
    mega<64, false, 0><<<2104, 256, 0, stream>>>(P);
  }

  // M5: tpose all 8 T1 panels
  {
    TPack T{};
    T.nseg = 8;
    T.t[0] = TSeg{X0a + 1 * 32, T1a0T, 192, 1500, 1536, 0};
    T.t[1] = TSeg{X0a + 4 * 32, T1b0T, 192, 1500, 1536, 24};
    T.t[2] = TSeg{X1a + 1 * 32, T1laT, 352, 6000, 6016, 48};
    T.t[3] = TSeg{X1a + 4 * 32, T1lbT, 352, 6000, 6016, 142};
    T.t[4] = TSeg{X1a + 6 * 32, T1uaT, 352, 6000, 6016, 236};
    T.t[5] = TSeg{X1a + 9 * 32, T1ubT, 352, 6000, 6016, 330};
    T.t[6] = TSeg{X2a + 1 * 32, T1a2T, 192, 4000, 4096, 424};
    T.t[7] = TSeg{X2a + 4 * 32, T1b2T, 192, 4000, 4096, 488};
    tpose_batch<<<552, 256, 0, stream>>>(T);
  }

  // M6: cheb pass 2 (T2 = 2*L@T1 - [a|b])
  {
    if (tier == 2) {
      Mega P{};
      P.nseg = 4;
      P.s[0] = seg(L0bf, nullptr, 24, 0, 1500, 1536, T1a0T, T1b0T,
                   2.f, X0a + 0 * 32, X0a + 3 * 32, 192, -1.f, nullptr, 0, 0,
                   X0a + 2 * 32, X0a + 5 * 32, 192, 384, 24, 4, 0);
      P.s[1] = seg(L1lbf, nullptr, 94, 0, 6000, 6016, T1laT, T1lbT,
                   2.f, X1a + 0 * 32, X1a + 3 * 32, 352, -1.f, nullptr, 0, 0,
                   X1a + 2 * 32, X1a + 5 * 32, 352, 768, 94, 8, 96);
      P.s[2] = seg(L1ubf, nullptr, 94, 0, 6000, 6016, T1uaT, T1ubT,
                   2.f, X1a + 3 * 32, X1a + 8 * 32, 352, -1.f, nullptr, 0, 0,
                   X1a + 7 * 32, X1a + 10 * 32, 352, 768, 94, 8, 848);
      P.s[3] = seg(L2bf, nullptr, 64, 0, 4000, 4096, T1a2T, T1b2T,
                   2.f, X2a + 0 * 32, X2a + 3 * 32, 192, -1.f, nullptr, 0, 0,
                   X2a + 2 * 32, X2a + 5 * 32, 192, 512, 63, 8, 1600);
      P.gemm_end = 2104; P.nconv = 0; P.conv_end = 2104; P.ntp = 0;
      mega<64, false, 1><<<2104, 256, 0, stream>>>(P);
    } else if (tier == 1) {
      Mega P{};
      P.nseg = 2;
      P.s[0] = seg(L1lbf, nullptr, 94, 0, 6000, 6016, T1laT, T1lbT,
                   2.f, X1a + 0 * 32, X1a + 3 * 32, 352, -1.f, nullptr, 0, 0,
                   X1a + 2 * 32, X1a + 5 * 32, 352, 768, 94, 8, 0);
      P.s[1] = seg(L1ubf, nullptr, 94, 0, 6000, 6016, T1uaT, T1ubT,
                   2.f, X1a + 3 * 32, X1a + 8 * 32, 352, -1.f, nullptr, 0, 0,
                   X1a + 7 * 32, X1a + 10 * 32, 352, 768, 94, 8, 752);
      P.gemm_end = 1504; P.nconv = 0; P.conv_end = 1504; P.ntp = 0;
      mega<64, false, 1><<<1504, 256, 0, stream>>>(P);
      Mega Q{};
      Q.nseg = 2;
      Q.s[0] = seg(L0, nullptr, 1500, 0, 1500, 1500, T1a0T, T1b0T,
                   2.f, X0a + 0 * 32, X0a + 3 * 32, 192, -1.f, nullptr, 0, 0,
                   X0a + 2 * 32, X0a + 5 * 32, 192, 384, 24, 4, 0);
      Q.s[1] = seg(L2, nullptr, 4000, 0, 4000, 4000, T1a2T, T1b2T,
                   2.f, X2a + 0 * 32, X2a + 3 * 32, 192, -1.f, nullptr, 0, 0,
                   X2a + 2 * 32, X2a + 5 * 32, 192, 512, 63, 8, 96);
      Q.gemm_end = 600; Q.nconv = 0; Q.conv_end = 600; Q.ntp = 0;
      mega<64, false, 0><<<600, 256, 0, stream>>>(Q);
    } else {
      Mega P{};
      P.nseg = 4;
      P.s[0] = seg(L0, nullptr, 1500, 0, 1500, 1500, T1a0T, T1b0T,
                   2.f, X0a + 0 * 32, X0a + 3 * 32, 192, -1.f, nullptr, 0, 0,
                   X0a + 2 * 32, X0a + 5 * 32, 192, 384, 24, 4, 0);
      P.s[1] = seg(L1l, nullptr, 6000, 0, 6000, 6000, T1laT, T1lbT,
                   2.f, X1a + 0 * 32, X1a + 3 * 32, 352, -1.f, nullptr, 0, 0,
                   X1a + 2 * 32, X1a + 5 * 32, 352, 768, 94, 8, 96);
      P.s[2] = seg(L1u, nullptr, 6000, 0, 6000, 6000, T1uaT, T1ubT,
                   2.f, X1a + 3 * 32, X1a + 8 * 32, 352, -1.f, nullptr, 0, 0,
                   X1a + 7 * 32, X1a + 10 * 32, 352, 768, 94, 8, 848);
      P.s[3] = seg(L2, nullptr, 4000, 0, 4000, 4000, T1a2T, T1b2T,
                   2.f, X2a + 0 * 32, X2a + 3 * 32, 192, -1.f, nullptr, 0, 0,
                   X2a + 2 * 32, X2a + 5 * 32, 192, 512, 63, 8, 1600);
      P.gemm_end = 2104; P.nconv = 0; P.conv_end = 2104; P.ntp = 0;
      mega<64, false, 0><<<2104, 256, 0, stream>>>(P);
    }
  }

  // M7: finals y = relu(X @ W)
  {
    Mega P{};
    P.nseg = 3;
    P.s[0] = seg(X0a, nullptr, 192, 0, 1500, 192, W0T, W0T,
                 1.f, nullptr, nullptr, 0, 0.f, nullptr, 0, 0,
                 out, nullptr, 32, 192, 24, 1, 0);
    P.s[1] = seg(X1a, nullptr, 352, 0, 6000, 352, W1T, W1T,
                 1.f, nullptr, nullptr, 0, 0.f, nullptr, 0, 0,
                 out + 48000, nullptr, 32, 384, 94, 1, 24);
    P.s[2] = seg(X2a, nullptr, 192, 0, 4000, 192, W2T, W2T,
                 1.f, nullptr, nullptr, 0, 0.f, nullptr, 0, 0,
                 out + 240000, nullptr, 32, 192, 63, 1, 118);
    P.gemm_end = 181; P.nconv = 0; P.conv_end = 181; P.ntp = 0;
    mega<32, true, 0><<<181, 256, 0, stream>>>(P);
  }
}

// Round 12
// 307.847 us; speedup vs baseline: 1.0970x; 1.0970x over previous
//
#include <hip/hip_runtime.h>
#include <stdint.h>

typedef __attribute__((ext_vector_type(4))) float f32x4;
typedef __attribute__((ext_vector_type(8))) short s16x8;
typedef unsigned short us;

static __device__ __forceinline__ us f2bf(float f) {
  union { float f; uint32_t u; } v; v.f = f;
  uint32_t u = v.u;
  u += 0x7fffu + ((u >> 16) & 1u);   // round-to-nearest-even bf16
  return (us)(u >> 16);
}

// mode: 0 none, 1 multiply, 2 multiply-by-safe-reciprocal
static __device__ __forceinline__ float dval(const float* dv, long r, long dstr, int mode) {
  if (!dv || mode == 0) return 1.f;
  float d = dv[r * dstr];
  if (mode == 2) return (d != 0.f) ? 1.f / d : 0.f;
  return d;
}

// ---------------- transpose tile: src f32 [n][32] (row stride lds_) -> dst bf16 [32][ldn] ----------------
static __device__ void tpose_tile(const float* __restrict__ src, long lds_, int n,
                                  const float* __restrict__ dv, long dstr, int mode,
                                  us* __restrict__ dst, int ldn, int tile,
                                  us (*sm)[72]) {
  const int t = threadIdx.x;
  const int r0 = tile * 64;
  {
    const int rr = t & 63;
    const int cg = t >> 6;
    const int gr = r0 + rr;
    float sc = 1.f;
    f32x4 v0 = {0.f, 0.f, 0.f, 0.f}, v1 = {0.f, 0.f, 0.f, 0.f};
    if (gr < n) {
      sc = dval(dv, gr, dstr, mode);
      const float* sp = src + (long)gr * lds_ + cg * 8;
      v0 = *(const f32x4*)sp;
      v1 = *(const f32x4*)(sp + 4);
    }
#pragma unroll
    for (int j = 0; j < 4; ++j) {
      sm[cg * 8 + j][rr] = f2bf(v0[j] * sc);
      sm[cg * 8 + 4 + j][rr] = f2bf(v1[j] * sc);
    }
  }
  __syncthreads();
  {
    const int f = t >> 3;
    const int nc = (t & 7) * 8;
    if (r0 + nc < ldn) {
      s16x8 v = *(const s16x8*)&sm[f][nc];
      *(s16x8*)(dst + (size_t)f * ldn + r0 + nc) = v;
    }
  }
}

static __device__ void convT_tile(const float* __restrict__ in, int ldi, int nI, int nC,
                                  us* __restrict__ outT, int ldoT, int bx, int by,
                                  us (*sT)[72]) {
  const int t = threadIdx.x;
  const int tc0 = bx * 64;
  const int tr0 = by * 64;
  const int c0 = (t & 15) * 4;
  const int r0 = (t >> 4) * 4;
  us ub[4][4];
#pragma unroll
  for (int j = 0; j < 4; ++j) {
    int gr = tr0 + r0 + j;
    f32x4 v = {0.f, 0.f, 0.f, 0.f};
    if (gr < nI) {
      const float* pI = in + (size_t)gr * ldi + tc0 + c0;
      if (tc0 + c0 + 3 < nC) {
        v = *(const f32x4*)pI;
      } else {
#pragma unroll
        for (int jj = 0; jj < 4; ++jj) if (tc0 + c0 + jj < nC) v[jj] = pI[jj];
      }
    }
#pragma unroll
    for (int jj = 0; jj < 4; ++jj) ub[j][jj] = f2bf(v[jj]);
  }
#pragma unroll
  for (int jj = 0; jj < 4; ++jj) {
    union { us u[4]; unsigned long long ll; } w;
#pragma unroll
    for (int j = 0; j < 4; ++j) w.u[j] = ub[j][jj];
    *(unsigned long long*)&sT[c0 + jj][r0] = w.ll;
  }
  __syncthreads();
#pragma unroll
  for (int p = 0; p < 2; ++p) {
    int orow = (t >> 3) + p * 32;
    int rcol = (t & 7) * 8;
    int grow = tc0 + orow;
    int gcol = tr0 + rcol;
    if (grow < nC && gcol < ldoT) {
      union { unsigned long long ll[2]; s16x8 v; } w;
      w.ll[0] = *(const unsigned long long*)&sT[orow][rcol];
      w.ll[1] = *(const unsigned long long*)&sT[orow][rcol + 4];
      *(s16x8*)(outT + (size_t)grow * ldoT + gcol) = w.v;
    }
  }
}

// ---------------- batched small transpose (standalone) ----------------
struct TSeg { const float* src; us* dst; int lds_, n, ldn, start; };
struct TPack { TSeg t[8]; int nseg; };

__global__ __launch_bounds__(256) void tpose_batch(TPack P) {
  __shared__ us sm[32][72];
  int b = blockIdx.x;
  int si = P.nseg - 1;
  while (si > 0 && P.t[si].start > b) --si;
  const TSeg s = P.t[si];
  tpose_tile(s.src, s.lds_, s.n, nullptr, 0, 0, s.dst, s.ldn, b - s.start, sm);
}

// ---------------- prep ----------------
__global__ __launch_bounds__(256) void prep(
    const float* __restrict__ x0, const float* __restrict__ x1, const float* __restrict__ x2,
    const float* __restrict__ D1, const float* __restrict__ D3, const float* __restrict__ D5,
    const float* __restrict__ W0, const float* __restrict__ W1, const float* __restrict__ W2,
    us* x0T, us* x0dT, us* x1T, us* x1dT, us* x2T, us* x2dT,
    us* W0T, us* W1T, us* W2T,
    float* __restrict__ X0a, float* __restrict__ X1a, float* __restrict__ X2a) {
  __shared__ us sm[32][72];
  int b = blockIdx.x;
  if (b < 24)  { tpose_tile(x0, 32, 1500, nullptr, 0, 0, x0T, 1536, b, sm); return; }
  b -= 24;
  if (b < 24)  { tpose_tile(x0, 32, 1500, D1, 1501, 2, x0dT, 1536, b, sm); return; }
  b -= 24;
  if (b < 94)  { tpose_tile(x1, 32, 6000, nullptr, 0, 0, x1T, 6016, b, sm); return; }
  b -= 94;
  if (b < 94)  { tpose_tile(x1, 32, 6000, D5, 6001, 2, x1dT, 6016, b, sm); return; }
  b -= 94;
  if (b < 63)  { tpose_tile(x2, 32, 4000, nullptr, 0, 0, x2T, 4032, b, sm); return; }
  b -= 63;
  if (b < 63)  { tpose_tile(x2, 32, 4000, D3, 4001, 1, x2dT, 4032, b, sm); return; }
  b -= 63;
  if (b < 3) {
    const float* W = (b == 0) ? W0 : ((b == 1) ? W1 : W2);
    us* dst = (b == 0) ? W0T : ((b == 1) ? W1T : W2T);
    const int K = (b == 1) ? 11 : 6;
    const int C = K * 32;
    const int CP = (b == 1) ? 384 : 192;
    for (int idx = threadIdx.x; idx < 32 * CP; idx += 256) {
      int o = idx / CP, j = idx - o * CP;
      float v = 0.f;
      if (j < C) { int k = j >> 5, i = j & 31; v = W[((long)i * 32 + o) * K + k]; }
      dst[(size_t)o * CP + j] = f2bf(v);
    }
    return;
  }
  b -= 3;
  const long V0 = 1500L * 48, V1 = 6000L * 88, V2 = 4000L * 48;
  for (long i = (long)b * 256 + threadIdx.x; i < V0 + V1 + V2; i += 512L * 256) {
    f32x4 v = {0.f, 0.f, 0.f, 0.f};
    float* dst;
    if (i < V0) {
      long r = i / 48; int c0 = (int)(i - r * 48) * 4;
      if (c0 < 32) v = *(const f32x4*)(x0 + r * 32 + c0);
      dst = X0a + r * 192 + c0;
    } else if (i < V0 + V1) {
      long j = i - V0; long r = j / 88; int c0 = (int)(j - r * 88) * 4;
      if (c0 >= 96 && c0 < 128) v = *(const f32x4*)(x1 + r * 32 + (c0 - 96));
      dst = X1a + r * 352 + c0;
    } else {
      long j = i - V0 - V1; long r = j / 48; int c0 = (int)(j - r * 48) * 4;
      if (c0 >= 96 && c0 < 128) v = *(const f32x4*)(x2 + r * 32 + (c0 - 96));
      dst = X2a + r * 192 + c0;
    }
    *(f32x4*)dst = v;
  }
}

// ---------------- mega: batched MFMA GEMM segs + convT segs + tpose segs (r7 proven core) ----------------
struct Seg {
  const void* A;
  const us* Bt0; const us* Bt1;
  const float* S0; const float* S1; const float* sv;
  float* C0; float* C1;
  float alpha, beta;
  int lda, ldS, sstr, ldc;
  int n_rows, n_k, ldb, smode, kchunk, tiles, ky, start;
};
struct CSeg { const float* in; us* out; int ldi, nI, nC, ldoT, cx, start; };
struct Mega {
  Seg s[4]; CSeg c[2]; TSeg t[2];
  int nseg, gemm_end, nconv, conv_end, ntp;
};

template <int F, bool RELU, typename AT>
__global__ __launch_bounds__(256) void mega(Mega P) {
  __shared__ __align__(16) us lds[64 * 128];
  const int b = blockIdx.x;
  if (b >= P.gemm_end) {
    if (b < P.conv_end) {
      int lb = b - P.gemm_end;
      int si = P.nconv - 1;
      while (si > 0 && P.c[si].start > lb) --si;
      const CSeg s = P.c[si];
      int l = lb - s.start;
      convT_tile(s.in, s.ldi, s.nI, s.nC, s.out, s.ldoT, l % s.cx, l / s.cx, (us(*)[72])lds);
    } else {
      int lb = b - P.conv_end;
      int si = P.ntp - 1;
      while (si > 0 && P.t[si].start > lb) --si;
      const TSeg s = P.t[si];
      tpose_tile(s.src, s.lds_, s.n, nullptr, 0, 0, s.dst, s.ldn, lb - s.start, (us(*)[72])lds);
    }
    return;
  }

  us* sA = lds;
  us* sX = lds + 64 * 64;

  int si = P.nseg - 1;
  while (si > 0 && P.s[si].start > b) --si;
  const Seg sg = P.s[si];
  const int local = b - sg.start;
  const int bx = local % sg.tiles;
  const int kidx = local / sg.tiles;

  const AT* __restrict__ A = (const AT*)sg.A;
  const int n_rows = sg.n_rows, n_k = sg.n_k, ldb = sg.ldb;

  const int tid = threadIdx.x;
  const int k_begin = kidx * sg.kchunk;
  const int k_end = min(n_k, k_begin + sg.kchunk);
  const int nsteps = (k_end - k_begin + 63) >> 6;

  const int srow = tid >> 2;
  const int sslot = tid & 3;
  const int kc_off = sslot * 16;
  const long arowg = (long)bx * 64 + srow;
  const bool arow_ok = arowg < n_rows;
  const bool xrow_ok = (F == 64) || (srow < 32);
  const us* xbase = ((srow < 32) ? sg.Bt0 : sg.Bt1) + (size_t)(srow & 31) * ldb;

  s16x8 abf0 = (s16x8)0, abf1 = (s16x8)0;
  f32x4 af0, af1, af2, af3;
  s16x8 x0r = (s16x8)0, x1r = (s16x8)0;

  auto load_tiles = [&](int k0) {
    int kc = k0 + kc_off;
    if constexpr (sizeof(AT) == 4) {
      af0 = f32x4{0, 0, 0, 0}; af1 = af0; af2 = af0; af3 = af0;
      if (arow_ok) {
        const float* ap = (const float*)A + (size_t)arowg * sg.lda + kc;
        if (kc + 15 < n_k) {
          af0 = *(const f32x4*)ap; af1 = *(const f32x4*)(ap + 4);
          af2 = *(const f32x4*)(ap + 8); af3 = *(const f32x4*)(ap + 12);
        } else {
#pragma unroll
          for (int j = 0; j < 4; ++j) {
            if (kc + j < n_k) af0[j] = ap[j];
            if (kc + 4 + j < n_k) af1[j] = ap[4 + j];
            if (kc + 8 + j < n_k) af2[j] = ap[8 + j];
            if (kc + 12 + j < n_k) af3[j] = ap[12 + j];
          }
        }
      }
    } else {
      abf0 = (s16x8)0; abf1 = (s16x8)0;
      if (arow_ok) {
        const us* ap = (const us*)A + (size_t)arowg * sg.lda + kc;
        if (kc + 15 < n_k) {
          abf0 = *(const s16x8*)ap; abf1 = *(const s16x8*)(ap + 8);
        } else {
#pragma unroll
          for (int j = 0; j < 8; ++j) {
            if (kc + j < n_k) abf0[j] = (short)ap[j];
            if (kc + 8 + j < n_k) abf1[j] = (short)ap[8 + j];
          }
        }
      }
    }
    if (xrow_ok) {
      x0r = *(const s16x8*)(xbase + kc);
      x1r = *(const s16x8*)(xbase + kc + 8);
    }
  };

  load_tiles(k_begin);

  const int wave = tid >> 6;
  const int lane = tid & 63;
  const int g = lane >> 4;
  const int r = lane & 15;
  const int wslot0 = ((2 * sslot) ^ (srow & 7)) * 8;
  const int wslot1 = ((2 * sslot + 1) ^ (srow & 7)) * 8;

  f32x4 acc[F / 16];
#pragma unroll
  for (int i = 0; i < F / 16; ++i) acc[i] = f32x4{0.f, 0.f, 0.f, 0.f};

  for (int s = 0; s < nsteps; ++s) {
    s16x8 pk0, pk1;
    if constexpr (sizeof(AT) == 4) {
#pragma unroll
      for (int j = 0; j < 4; ++j) {
        pk0[j] = (short)f2bf(af0[j]); pk0[4 + j] = (short)f2bf(af1[j]);
        pk1[j] = (short)f2bf(af2[j]); pk1[4 + j] = (short)f2bf(af3[j]);
      }
    } else { pk0 = abf0; pk1 = abf1; }
    *(s16x8*)&sA[srow * 64 + wslot0] = pk0;
    *(s16x8*)&sA[srow * 64 + wslot1] = pk1;
    if (xrow_ok) {
      *(s16x8*)&sX[srow * 64 + wslot0] = x0r;
      *(s16x8*)&sX[srow * 64 + wslot1] = x1r;
    }
    __syncthreads();
    if (s + 1 < nsteps) load_tiles(k_begin + (s + 1) * 64);

    const int arow = wave * 16 + r;
#pragma unroll
    for (int kk = 0; kk < 2; ++kk) {
      s16x8 afr = *(s16x8*)&sA[arow * 64 + (((kk * 4 + g) ^ (arow & 7)) << 3)];
#pragma unroll
      for (int nt = 0; nt < F / 16; ++nt) {
        int xc = nt * 16 + r;
        s16x8 bfr = *(s16x8*)&sX[xc * 64 + (((kk * 4 + g) ^ (xc & 7)) << 3)];
        acc[nt] = __builtin_amdgcn_mfma_f32_16x16x32_bf16(afr, bfr, acc[nt], 0, 0, 0);
      }
    }
    __syncthreads();
  }

  float svv[4];
#pragma unroll
  for (int j = 0; j < 4; ++j) {
    long row = (long)bx * 64 + wave * 16 + g * 4 + j;
    svv[j] = (row < n_rows) ? dval(sg.sv, row, sg.sstr, sg.smode) : 0.f;
  }
#pragma unroll
  for (int nt = 0; nt < F / 16; ++nt) {
    float* C = (F == 64 && nt >= 2) ? sg.C1 : sg.C0;
    const float* S = (F == 64 && nt >= 2) ? sg.S1 : sg.S0;
    int col = ((F == 64) ? (nt & 1) : nt) * 16 + r;
#pragma unroll
    for (int j = 0; j < 4; ++j) {
      long row = (long)bx * 64 + wave * 16 + g * 4 + j;
      if (row < n_rows) {
        float v = sg.alpha * acc[nt][j] * svv[j];
        if (S && (sg.ky == 1 || kidx == 0)) v += sg.beta * S[row * (size_t)sg.ldS + col];
        if (sg.ky > 1) {
          atomicAdd(&C[row * (size_t)sg.ldc + col], v);
        } else {
          if (RELU) v = fmaxf(v, 0.0f);
          C[row * (size_t)sg.ldc + col] = v;
        }
      }
    }
  }
}

// ---------------- fallback helpers ----------------
__global__ void colcopy(float* __restrict__ dst, const float* __restrict__ src, int n,
                        const float* __restrict__ dv, long dstr, int mode) {
  int idx = blockIdx.x * 256 + threadIdx.x;
  if (idx >= n * 32) return;
  dst[idx] = src[idx] * dval(dv, idx >> 5, dstr, mode);
}
__global__ void scale_ld(float* __restrict__ dst, long ld, int n,
                         const float* __restrict__ dv, long dstr, int mode) {
  int idx = blockIdx.x * 256 + threadIdx.x;
  if (idx >= n * 32) return;
  dst[(size_t)(idx >> 5) * ld + (idx & 31)] *= dval(dv, idx >> 5, dstr, mode);
}
__global__ __launch_bounds__(256) void mm_at(
    const float* __restrict__ A, int lda, int m,
    const float* __restrict__ X,
    float* __restrict__ C, int ldc, int n, int kchunk) {
  const int fg = threadIdx.x & 3;
  const int cg = threadIdx.x >> 2;
  const int c = blockIdx.x * 256 + cg * 4;
  const int k0 = blockIdx.y * kchunk;
  const int k1 = min(m, k0 + kchunk);
  const int f = fg * 8;
  float acc[4][8];
#pragma unroll
  for (int a = 0; a < 4; ++a)
#pragma unroll
    for (int bb = 0; bb < 8; ++bb) acc[a][bb] = 0.f;
  for (int k = k0; k < k1; ++k) {
    const float* Ar = A + (size_t)k * lda + c;
    f32x4 a;
    if (c + 3 < n) a = *(const f32x4*)Ar;
    else {
      a = f32x4{0.f, 0.f, 0.f, 0.f};
#pragma unroll
      for (int j = 0; j < 4; ++j) if (c + j < n) a[j] = Ar[j];
    }
    f32x4 xa = *(const f32x4*)(X + (size_t)k * 32 + f);
    f32x4 xb = *(const f32x4*)(X + (size_t)k * 32 + f + 4);
#pragma unroll
    for (int cc = 0; cc < 4; ++cc)
#pragma unroll
      for (int jj = 0; jj < 4; ++jj) {
        acc[cc][jj] += a[cc] * xa[jj];
        acc[cc][4 + jj] += a[cc] * xb[jj];
      }
  }
  if (c >= n) return;
#pragma unroll
  for (int cc = 0; cc < 4; ++cc) {
    if (c + cc >= n) break;
#pragma unroll
    for (int jj = 0; jj < 8; ++jj)
      atomicAdd(&C[(size_t)(c + cc) * ldc + f + jj], acc[cc][jj]);
  }
}

// ---------------- host ----------------

extern "C" void kernel_launch(void* const* d_in, const int* in_sizes, int n_in,
                              void* d_out, int out_size, void* d_ws, size_t ws_size,
                              hipStream_t stream) {
  (void)in_sizes; (void)n_in; (void)out_size;
  const float* x0  = (const float*)d_in[0];
  const float* x1  = (const float*)d_in[1];
  const float* x2  = (const float*)d_in[2];
  const float* B1  = (const float*)d_in[3];
  const float* B2  = (const float*)d_in[4];
  const float* L0  = (const float*)d_in[5];
  const float* L1l = (const float*)d_in[6];
  const float* L1u = (const float*)d_in[7];
  const float* L2  = (const float*)d_in[8];
  const float* D1  = (const float*)d_in[9];
  const float* D2  = (const float*)d_in[10];
  const float* D3  = (const float*)d_in[11];
  const float* D5  = (const float*)d_in[12];
  const float* W0  = (const float*)d_in[13];
  const float* W1  = (const float*)d_in[14];
  const float* W2  = (const float*)d_in[15];
  float* out = (float*)d_out;

  char* p = (char*)d_ws;
  auto alloc = [&](size_t b) { char* r = p; p += (b + 255) & ~(size_t)255; return r; };

  us* x0T   = (us*)alloc((size_t)32 * 1536 * 2);
  us* x0dT  = (us*)alloc((size_t)32 * 1536 * 2);
  us* x1T   = (us*)alloc((size_t)32 * 6016 * 2);
  us* x1dT  = (us*)alloc((size_t)32 * 6016 * 2);
  us* x2T   = (us*)alloc((size_t)32 * 4032 * 2);
  us* x2dT  = (us*)alloc((size_t)32 * 4032 * 2);
  us* x0pT  = (us*)alloc((size_t)32 * 1536 * 2);
  us* x1nT  = (us*)alloc((size_t)32 * 6016 * 2);
  us* x1pT  = (us*)alloc((size_t)32 * 6016 * 2);
  us* x2nT  = (us*)alloc((size_t)32 * 4032 * 2);
  us* T1a0T = (us*)alloc((size_t)32 * 1536 * 2);
  us* T1b0T = (us*)alloc((size_t)32 * 1536 * 2);
  us* T1laT = (us*)alloc((size_t)32 * 6016 * 2);
  us* T1lbT = (us*)alloc((size_t)32 * 6016 * 2);
  us* T1uaT = (us*)alloc((size_t)32 * 6016 * 2);
  us* T1ubT = (us*)alloc((size_t)32 * 6016 * 2);
  us* T1a2T = (us*)alloc((size_t)32 * 4032 * 2);
  us* T1b2T = (us*)alloc((size_t)32 * 4032 * 2);
  us* W0T   = (us*)alloc((size_t)32 * 192 * 2);
  us* W1T   = (us*)alloc((size_t)32 * 384 * 2);
  us* W2T   = (us*)alloc((size_t)32 * 192 * 2);

  float* X0a = (float*)alloc((size_t)1500 * 192 * 4);
  float* X1a = (float*)alloc((size_t)6000 * 352 * 4);
  float* X2a = (float*)alloc((size_t)4000 * 192 * 4);

  float* z0  = (float*)alloc((size_t)1500 * 32 * 4);
  float* sx1 = (float*)alloc((size_t)6000 * 32 * 4);

  size_t used = (size_t)(p - (char*)d_ws);
  const size_t needB = (size_t)6000 * 1536 * 2 + (size_t)4000 * 6016 * 2 + 1024;
  bool haveB = used + needB <= ws_size;
  us *B1t = nullptr, *B2t = nullptr;
  if (haveB) {
    B1t = (us*)alloc((size_t)6000 * 1536 * 2);
    B2t = (us*)alloc((size_t)4000 * 6016 * 2);
  }

  auto nb = [](long t) { return (unsigned)((t + 255) / 256); };
  auto seg = [](const void* A, int lda, int n_rows, int n_k,
                const us* Bt0, const us* Bt1, int ldb,
                float alpha, const float* S0, const float* S1, int ldS, float beta,
                const float* sv, int sstr, int smode,
                float* C0, float* C1, int ldc,
                int kchunk, int tiles, int ky, int start) {
    Seg s;
    s.A = A; s.Bt0 = Bt0; s.Bt1 = Bt1; s.S0 = S0; s.S1 = S1; s.sv = sv;
    s.C0 = C0; s.C1 = C1; s.alpha = alpha; s.beta = beta;
    s.lda = lda; s.ldS = ldS; s.sstr = sstr; s.ldc = ldc;
    s.n_rows = n_rows; s.n_k = n_k; s.ldb = ldb; s.smode = smode;
    s.kchunk = kchunk; s.tiles = tiles; s.ky = ky; s.start = start;
    return s;
  };

  // 1. prep
  prep<<<877, 256, 0, stream>>>(x0, x1, x2, D1, D3, D5, W0, W1, W2,
                                x0T, x0dT, x1T, x1dT, x2T, x2dT, W0T, W1T, W2T,
                                X0a, X1a, X2a);

  // M1: B-GEMMs (x0p, x1p) + convT(B1->B1t, B2->B2t)
  {
    Mega P{};
    P.nseg = 2;
    P.s[0] = seg(B1, 6000, 1500, 6000, x1T, x1T, 6016,
                 1.f, nullptr, nullptr, 0, 0.f, D1, 1501, 2,
                 X0a + 3 * 32, nullptr, 192, 768, 24, 8, 0);               // 192 blocks
    P.s[1] = seg(B2, 4000, 6000, 4000, x2dT, x2dT, 4032,
                 1.f, nullptr, nullptr, 0, 0.f, nullptr, 0, 0,
                 X1a + 8 * 32, nullptr, 352, 512, 94, 8, 192);             // 752 blocks
    P.gemm_end = 944;
    if (haveB) {
      P.nconv = 2;
      P.c[0] = CSeg{B1, B1t, 6000, 1500, 6000, 1536, 94, 0};
      P.c[1] = CSeg{B2, B2t, 4000, 6000, 4000, 6016, 63, 2256};
      P.conv_end = 944 + 8178;
    } else {
      P.nconv = 0; P.conv_end = 944;
    }
    P.ntp = 0;
    mega<32, false, float><<<P.conv_end, 256, 0, stream>>>(P);
  }

  // M2: Bt-GEMMs (x1n, x2n) + tpose(x0p, x1p)
  if (haveB) {
    Mega P{};
    P.nseg = 2;
    P.s[0] = seg(B1t, 1536, 6000, 1536, x0dT, x0dT, 1536,
                 1.f, nullptr, nullptr, 0, 0.f, D2, 6001, 1,
                 X1a + 0 * 32, nullptr, 352, 384, 94, 4, 0);               // 376 blocks
    P.s[1] = seg(B2t, 6016, 4000, 6016, x1dT, x1dT, 6016,
                 1.f, nullptr, nullptr, 0, 0.f, nullptr, 0, 0,
                 X2a + 0 * 32, nullptr, 192, 768, 63, 8, 376);             // 504 blocks
    P.gemm_end = 880;
    P.nconv = 0; P.conv_end = 880;
    P.ntp = 2;
    P.t[0] = TSeg{X0a + 3 * 32, x0pT, 192, 1500, 1536, 0};
    P.t[1] = TSeg{X1a + 8 * 32, x1pT, 352, 6000, 6016, 24};
    mega<32, false, us><<<998, 256, 0, stream>>>(P);
  } else {
    colcopy<<<nb(1500L * 32), 256, 0, stream>>>(z0, x0, 1500, D1, 1501, 2);
    mm_at<<<dim3(24, 24), 256, 0, stream>>>(B1, 6000, 1500, z0, X1a + 0 * 32, 352, 6000, 63);
    scale_ld<<<nb(6000L * 32), 256, 0, stream>>>(X1a + 0 * 32, 352, 6000, D2, 6001, 1);
    colcopy<<<nb(6000L * 32), 256, 0, stream>>>(sx1, x1, 6000, D5, 6001, 2);
    mm_at<<<dim3(16, 32), 256, 0, stream>>>(B2, 4000, 6000, sx1, X2a + 0 * 32, 192, 4000, 188);
    TPack T{};
    T.nseg = 2;
    T.t[0] = TSeg{X0a + 3 * 32, x0pT, 192, 1500, 1536, 0};
    T.t[1] = TSeg{X1a + 8 * 32, x1pT, 352, 6000, 6016, 24};
    tpose_batch<<<118, 256, 0, stream>>>(T);
  }

  // M3: tpose x1n, x2n
  {
    TPack T{};
    T.nseg = 2;
    T.t[0] = TSeg{X1a + 0 * 32, x1nT, 352, 6000, 6016, 0};
    T.t[1] = TSeg{X2a + 0 * 32, x2nT, 192, 4000, 4032, 94};
    tpose_batch<<<157, 256, 0, stream>>>(T);
  }

  // M4: cheb pass 1 (T1 = L @ [a|b]); no side-products, moderate ky (atomic amp ~4x max)
  {
    Mega P{};
    P.nseg = 4;
    P.s[0] = seg(L0, 1500, 1500, 1500, x0T, x0pT, 1536,
                 1.f, nullptr, nullptr, 0, 0.f, nullptr, 0, 0,
                 X0a + 1 * 32, X0a + 4 * 32, 192, 768, 24, 2, 0);          // 48
    P.s[1] = seg(L1l, 6000, 6000, 6000, x1nT, x1T, 6016,
                 1.f, nullptr, nullptr, 0, 0.f, nullptr, 0, 0,
                 X1a + 1 * 32, X1a + 4 * 32, 352, 1536, 94, 4, 48);        // 376
    P.s[2] = seg(L1u, 6000, 6000, 6000, x1T, x1pT, 6016,
                 1.f, nullptr, nullptr, 0, 0.f, nullptr, 0, 0,
                 X1a + 6 * 32, X1a + 9 * 32, 352, 1536, 94, 4, 424);       // 376
    P.s[3] = seg(L2, 4000, 4000, 4000, x2nT, x2T, 4032,
                 1.f, nullptr, nullptr, 0, 0.f, nullptr, 0, 0,
                 X2a + 1 * 32, X2a + 4 * 32, 192, 1024, 63, 4, 800);       // 252
    P.gemm_end = 1052; P.nconv = 0; P.conv_end = 1052; P.ntp = 0;
    mega<64, false, float><<<1052, 256, 0, stream>>>(P);
  }

  // M5: tpose all 8 T1 panels
  {
    TPack T{};
    T.nseg = 8;
    T.t[0] = TSeg{X0a + 1 * 32, T1a0T, 192, 1500, 1536, 0};
    T.t[1] = TSeg{X0a + 4 * 32, T1b0T, 192, 1500, 1536, 24};
    T.t[2] = TSeg{X1a + 1 * 32, T1laT, 352, 6000, 6016, 48};
    T.t[3] = TSeg{X1a + 4 * 32, T1lbT, 352, 6000, 6016, 142};
    T.t[4] = TSeg{X1a + 6 * 32, T1uaT, 352, 6000, 6016, 236};
    T.t[5] = TSeg{X1a + 9 * 32, T1ubT, 352, 6000, 6016, 330};
    T.t[6] = TSeg{X2a + 1 * 32, T1a2T, 192, 4000, 4032, 424};
    T.t[7] = TSeg{X2a + 4 * 32, T1b2T, 192, 4000, 4032, 487};
    tpose_batch<<<550, 256, 0, stream>>>(T);
  }

  // M6: cheb pass 2 (T2 = 2*L@T1 - [a|b]); f32 L, L3-warm from M4
  {
    Mega P{};
    P.nseg = 4;
    P.s[0] = seg(L0, 1500, 1500, 1500, T1a0T, T1b0T, 1536,
                 2.f, X0a + 0 * 32, X0a + 3 * 32, 192, -1.f, nullptr, 0, 0,
                 X0a + 2 * 32, X0a + 5 * 32, 192, 768, 24, 2, 0);
    P.s[1] = seg(L1l, 6000, 6000, 6000, T1laT, T1lbT, 6016,
                 2.f, X1a + 0 * 32, X1a + 3 * 32, 352, -1.f, nullptr, 0, 0,
                 X1a + 2 * 32, X1a + 5 * 32, 352, 1536, 94, 4, 48);
    P.s[2] = seg(L1u, 6000, 6000, 6000, T1uaT, T1ubT, 6016,
                 2.f, X1a + 3 * 32, X1a + 8 * 32, 352, -1.f, nullptr, 0, 0,
                 X1a + 7 * 32, X1a + 10 * 32, 352, 1536, 94, 4, 424);
    P.s[3] = seg(L2, 4000, 4000, 4000, T1a2T, T1b2T, 4032,
                 2.f, X2a + 0 * 32, X2a + 3 * 32, 192, -1.f, nullptr, 0, 0,
                 X2a + 2 * 32, X2a + 5 * 32, 192, 1024, 63, 4, 800);
    P.gemm_end = 1052; P.nconv = 0; P.conv_end = 1052; P.ntp = 0;
    mega<64, false, float><<<1052, 256, 0, stream>>>(P);
  }

  // M7: finals y = relu(X @ W)
  {
    Mega P{};
    P.nseg = 3;
    P.s[0] = seg(X0a, 192, 1500, 192, W0T, W0T, 192,
                 1.f, nullptr, nullptr, 0, 0.f, nullptr, 0, 0,
                 out, nullptr, 32, 192, 24, 1, 0);
    P.s[1] = seg(X1a, 352, 6000, 352, W1T, W1T, 384,
                 1.f, nullptr, nullptr, 0, 0.f, nullptr, 0, 0,
                 out + 48000, nullptr, 32, 384, 94, 1, 24);
    P.s[2] = seg(X2a, 192, 4000, 192, W2T, W2T, 192,
                 1.f, nullptr, nullptr, 0, 0.f, nullptr, 0, 0,
                 out + 240000, nullptr, 32, 192, 63, 1, 118);
    P.gemm_end = 181; P.nconv = 0; P.conv_end = 181; P.ntp = 0;
    mega<32, true, float><<<181, 256, 0, stream>>>(P);
  }
}